// Round 2
// baseline (302.895 us; speedup 1.0000x reference)
//
#include <hip/hip_runtime.h>

// RotaryEmbedding2D: out[b,s] is a 64x64 block-diagonal rotation matrix.
// B=16, S=1024, D=64, q=16, h=32. BASE=10000, SCALE=1.
// Row 2h:   col 2h = cos, col 2h+1 = -sin
// Row 2h+1: col 2h = sin, col 2h+1 =  cos
// 256 MiB fp32 output -> pure write-BW bound.
//
// v3: amortize per-block overhead. 2048 blocks (8/CU), each block handles
// 8 bs values = 128 KB of contiguous output. Phase 1: each thread computes
// one sincos into a 2KB LDS table (8 bs x 32 half-indices), one barrier.
// Phase 2: 32 full-width float4 stores per thread, value merged via
// predicated select -> every store instruction has all 64 lanes active
// (no partial cachelines), back-to-back stores keep the store queue deep,
// exactly like the 6.6 TB/s fillBuffer kernel.
//
// Per-thread closed form (within one bs, groups g = t + 256k, k=0..3):
//   row = (t>>4) + 16k, colgroup = t&15. Nonzero pair of row r lives in
//   colgroup r>>2 = (t>>4)>>2 + 4k, so thread t has at most ONE special
//   group: diff = (t&15) - (t>>6... (t>>4)>>2); special iff diff in
//   {0,4,8,12}, at k* = diff>>2. row*, h* = row*>>1 are bs-independent.

#define NBS  16384          // B*S
#define BSPB 8              // bs per block
#define NBLK (NBS / BSPB)   // 2048 blocks = 8 per CU

__global__ __launch_bounds__(256) void rope2d_kernel(
    const float* __restrict__ spa,   // (B,S,2)
    float* __restrict__ out)         // (B,S,64,64)
{
    const int t   = threadIdx.x;           // 0..255
    const int bs0 = blockIdx.x * BSPB;

    __shared__ float ssin[BSPB * 32];
    __shared__ float scos[BSPB * 32];

    // Phase 1: one sincos per thread. m = bs index within block, h = half-idx.
    {
        const int m = t >> 5;              // 0..7
        const int h = t & 31;              // 0..31
        const float xy   = spa[(bs0 + m) * 2 + (h >> 4)];
        // inv_freq = 10000^(-(h%16)/16) = exp2(-(h%16) * log2(10000)/16)
        const float invf = exp2f(-(float)(h & 15) * 0.83048202372184059f);
        const float a    = xy * invf;
        ssin[t] = sinf(a);                 // t == m*32 + h
        scos[t] = cosf(a);
    }
    __syncthreads();

    // Per-thread special-group geometry (bs-independent).
    const int cg    = t & 15;              // colgroup
    const int rbase = t >> 4;              // 0..15 (row base)
    const int diff  = cg - (rbase >> 2);
    const bool has  = (diff >= 0) && ((diff & 3) == 0);
    const int ks    = diff >> 2;           // special k (valid when has)
    const int rows  = rbase + (ks << 4);   // special row
    const int hs    = (rows >> 1) & 31;    // its half-index
    const int odd   = rows & 1;
    const int hi    = rows & 2;

    float4* __restrict__ outv = (float4*)out + (size_t)bs0 * 1024 + t;
    const float4 z4 = make_float4(0.f, 0.f, 0.f, 0.f);

    #pragma unroll
    for (int m = 0; m < BSPB; ++m) {
        float4 vs = z4;
        if (has) {
            const float s  = ssin[(m << 5) + hs];
            const float c  = scos[(m << 5) + hs];
            const float e0 = odd ? s :  c;
            const float e1 = odd ? c : -s;
            if (hi) { vs.z = e0; vs.w = e1; }
            else    { vs.x = e0; vs.y = e1; }
        }
        #pragma unroll
        for (int k = 0; k < 4; ++k) {
            // k compile-time, ks runtime: predicated select, all lanes store.
            // When !has, vs == z4, so a spurious k==ks match still writes zero.
            outv[m * 1024 + k * 256] = (k == ks) ? vs : z4;
        }
    }
}

extern "C" void kernel_launch(void* const* d_in, const int* in_sizes, int n_in,
                              void* d_out, int out_size, void* d_ws, size_t ws_size,
                              hipStream_t stream) {
    const float* spa = (const float*)d_in[0];
    float* out = (float*)d_out;
    rope2d_kernel<<<NBLK, 256, 0, stream>>>(spa, out);
}

// Round 3
// 261.429 us; speedup vs baseline: 1.1586x; 1.1586x over previous
//
#include <hip/hip_runtime.h>

// RotaryEmbedding2D: out[b,s] is a 64x64 block-diagonal rotation matrix.
// B=16, S=1024, D=64, q=16, h=32. BASE=10000, SCALE=1.
// Row 2h:   col 2h = cos, col 2h+1 = -sin
// Row 2h+1: col 2h = sin, col 2h+1 =  cos
// 256 MiB fp32 output -> pure write-BW bound.
//
// v4: v2's closed-form no-LDS structure (16384 blocks — best measured grid),
// but (a) every store is full-width 64-lane via predicated select (no exec
// holes, no partial cachelines), and (b) ALL stores are NON-TEMPORAL.
// Rationale: output (256 MiB) == L3 size; the harness's 1 GiB poison fill
// leaves ~256 MiB of dirty lines in L3, and plain write-allocating stores
// evict them inside OUR timing window (~2x traffic -> the ~90 us floor all
// prior variants hit). nt stores bypass allocation: our 256 MiB goes
// straight to HBM and the poison writeback stays out of our window.
//
// Per-thread closed form (groups g = t + 256k, k=0..3):
//   row = (t>>4) + 16k, colgroup = t&15. Nonzero pair of row r lives in
//   colgroup r>>2, so thread t has at most ONE special group:
//   diff = (t&15) - ((t>>4)>>2); special iff diff in {0,4,8,12}, k* = diff>>2.
//   Bijective: row r <-> thread ((r&15)<<4)|(r>>2) at k = r>>4.

#define NBS 16384   // B*S

typedef float f4 __attribute__((ext_vector_type(4)));

__global__ __launch_bounds__(256) void rope2d_kernel(
    const float* __restrict__ spa,   // (B,S,2)
    float* __restrict__ out)         // (B,S,64,64)
{
    const int bs = blockIdx.x;   // 0..16383
    const int t  = threadIdx.x;  // 0..255

    // Block-uniform -> early s_load_dwordx2; hides under the stores.
    const float xu = spa[bs * 2 + 0];
    const float yu = spa[bs * 2 + 1];

    const int  cg    = t & 15;            // colgroup (constant over k)
    const int  rbase = t >> 4;            // row base (k=0 row)
    const int  diff  = cg - (rbase >> 2);
    const bool has   = (diff >= 0) && ((diff & 3) == 0);
    const int  ks    = has ? (diff >> 2) : -1;  // -1 sentinel: never matches k
    const int  ksv   = has ? (diff >> 2) : 0;   // clamped for index math

    // Compute the (single, possible) nonzero group's value in ALL lanes;
    // lanes with ks==-1 produce a value that is never selected.
    const int rows = rbase + (ksv << 4);  // special row 0..63
    const int h    = rows >> 1;           // half-index 0..31
    const float xy   = (h & 16) ? yu : xu;
    // inv_freq = 10000^(-(h%16)/16) = exp2(-(h%16) * log2(10000)/16)
    const float invf = exp2f(-(float)(h & 15) * 0.83048202372184059f);
    const float a = xy * invf;
    const float s = sinf(a);
    const float c = cosf(a);
    const float e0 = (rows & 1) ? s :  c;
    const float e1 = (rows & 1) ? c : -s;
    f4 vs = (f4)(0.f);
    if (rows & 2) { vs.z = e0; vs.w = e1; }   // pair at offset 2 in group
    else          { vs.x = e0; vs.y = e1; }   // pair at offset 0

    f4* __restrict__ outv = (f4*)out + (size_t)bs * 1024 + t;
    const f4 z4 = (f4)(0.f);

    #pragma unroll
    for (int k = 0; k < 4; ++k) {
        // k is compile-time, ks runtime: per-lane cndmask select; all 64
        // lanes store full 16B -> fully coalesced 1KB/wave, non-temporal.
        f4 v = (k == ks) ? vs : z4;
        __builtin_nontemporal_store(v, &outv[k * 256]);
    }
}

extern "C" void kernel_launch(void* const* d_in, const int* in_sizes, int n_in,
                              void* d_out, int out_size, void* d_ws, size_t ws_size,
                              hipStream_t stream) {
    const float* spa = (const float*)d_in[0];
    float* out = (float*)d_out;
    rope2d_kernel<<<NBS, 256, 0, stream>>>(spa, out);
}